// Round 9
// baseline (177.242 us; speedup 1.0000x reference)
//
#include <hip/hip_runtime.h>

// Causal self-attention fwd: B=2 S=4096 H=16 D=64, fp32 in/out, bf16 MFMA compute.
// R9 = R8 with ONE change: __launch_bounds__(256,4) -> (256,2). Bisecting the R7/R8
// identical-absmax failure (2.87e30 = bf16 0x7211 garbage through V): remap proven
// bijective, inner loop byte-identical to validated R6 -> suspect is the VGPR cap 128
// forced by lb(,4) (R6 ran at 100 VGPR under lb(,2)). lb(,2) still gives 4 blocks/CU
// with 1024 blocks (VGPR 100 -> 5 waves/EU limit; LDS 18.4KB -> 8 blocks/CU limit).

#define S_LEN 4096
#define NHEAD 16
#define HDIM 64
#define QBLK 128
#define KVBLK 64
#define NQT (S_LEN / QBLK)  // 32
#define LDK 72
#define ROWSTRIDE (3 * NHEAD * HDIM)  // 3072 floats between consecutive s

using bf16x8 = __attribute__((ext_vector_type(8))) short;
using bf16x4 = __attribute__((ext_vector_type(4))) short;
using f32x4  = __attribute__((ext_vector_type(4))) float;

#define MFMA32(A, B, C) __builtin_amdgcn_mfma_f32_16x16x32_bf16((A), (B), (C), 0, 0, 0)
#define MFMA16(A, B, C) __builtin_amdgcn_mfma_f32_16x16x16bf16_1k((A), (B), (C), 0, 0, 0)

#if __has_builtin(__builtin_amdgcn_exp2f)
#define EXP2F(x) __builtin_amdgcn_exp2f(x)
#else
#define EXP2F(x) exp2f(x)
#endif

__device__ __forceinline__ int f2bf2(float lo, float hi) {
  int r;
  asm("v_cvt_pk_bf16_f32 %0, %1, %2" : "=v"(r) : "v"(lo), "v"(hi));
  return r;  // low 16 = bf16(lo), high 16 = bf16(hi)
}

__global__ __launch_bounds__(256, 2)
void attn_fwd(const float* __restrict__ qkv, float* __restrict__ out) {
  __shared__ short Ks[KVBLK][LDK] __attribute__((aligned(16)));   // K[kv][d] bf16
  __shared__ short VTs[HDIM][LDK] __attribute__((aligned(16)));   // V^T[d][kv] bf16

  // ---- balanced block remap (bijective; co-resident CU-set shares bh, 132 steps) ----
  const int flat = (int)blockIdx.x + 32 * (int)blockIdx.y;  // 0..1023
  const int u    = flat & 255;
  const int j    = flat >> 8;          // 0..3
  const int bh   = u >> 3;             // 0..31
  const int t8   = u & 7;              // 0..7
  const int qt   = (j == 0) ? t8 : (j == 1) ? 31 - t8 : (j == 2) ? 8 + t8 : 23 - t8;

  const int b    = bh >> 4;   // H=16
  const int h    = bh & 15;
  const int tid  = threadIdx.x;
  const int wid  = tid >> 6;   // 0..3
  const int lane = tid & 63;
  const int lq   = lane & 15;
  const int lg   = lane >> 4;

  const float* basep = qkv + (size_t)b * S_LEN * ROWSTRIDE + h * HDIM;
  const float* kbase = basep + NHEAD * HDIM;       // t=1
  const float* vbase = basep + 2 * NHEAD * HDIM;   // t=2

  // ---- staging (R6-validated): each thread owns a 4x4 micro-tile of K and of V ----
  const int rb = (tid >> 4) * 4;  // kv row base within tile
  const int cb = (tid & 15) * 4;  // d col base

  f32x4 kreg[4], vreg[4];
  auto load_tile = [&](int kvt) {
    const int kr = kvt * KVBLK + rb;
#pragma unroll
    for (int i = 0; i < 4; ++i) {
      kreg[i] = *reinterpret_cast<const f32x4*>(kbase + (size_t)(kr + i) * ROWSTRIDE + cb);
      vreg[i] = *reinterpret_cast<const f32x4*>(vbase + (size_t)(kr + i) * ROWSTRIDE + cb);
    }
  };
  auto store_tile = [&]() {
#pragma unroll
    for (int i = 0; i < 4; ++i) {
      union { bf16x4 v; int w[2]; } kk;
      kk.w[0] = f2bf2(kreg[i][0], kreg[i][1]);
      kk.w[1] = f2bf2(kreg[i][2], kreg[i][3]);
      *reinterpret_cast<bf16x4*>(&Ks[rb + i][cb]) = kk.v;
    }
#pragma unroll
    for (int e = 0; e < 4; ++e) {
      union { bf16x4 v; int w[2]; } vv;
      vv.w[0] = f2bf2(vreg[0][e], vreg[1][e]);
      vv.w[1] = f2bf2(vreg[2][e], vreg[3][e]);
      *reinterpret_cast<bf16x4*>(&VTs[cb + e][rb]) = vv.v;
    }
  };

  const float SC = 0.18033688011112042f;  // (1/8) * log2(e)

  const int wq = qt * QBLK + wid * 32;  // this wave's first q row (32 rows)

  // ---- Q fragments (B-operand: col=q=lq, k=d=8*lg+jj+32*t) for rt=0,1 ----
  bf16x8 qf[2][2];
#pragma unroll
  for (int rt = 0; rt < 2; ++rt) {
    const float* qp = basep + (size_t)(wq + rt * 16 + lq) * ROWSTRIDE + 8 * lg;
#pragma unroll
    for (int t = 0; t < 2; ++t) {
      f32x4 x0 = *reinterpret_cast<const f32x4*>(qp + 32 * t);
      f32x4 x1 = *reinterpret_cast<const f32x4*>(qp + 32 * t + 4);
      union { bf16x8 v; int w[4]; } uq;
      uq.w[0] = f2bf2(x0[0] * SC, x0[1] * SC);
      uq.w[1] = f2bf2(x0[2] * SC, x0[3] * SC);
      uq.w[2] = f2bf2(x1[0] * SC, x1[1] * SC);
      uq.w[3] = f2bf2(x1[2] * SC, x1[3] * SC);
      qf[rt][t] = uq.v;
    }
  }

  f32x4 acc[2][4];
#pragma unroll
  for (int rt = 0; rt < 2; ++rt)
#pragma unroll
    for (int dt = 0; dt < 4; ++dt)
      acc[rt][dt] = (f32x4){0.f, 0.f, 0.f, 0.f};

  float mrun[2] = {-1e30f, -1e30f};
  float lrun[2] = {0.f, 0.f};

  const int nkv = 2 * qt + 2;  // causal: kv tiles 0 .. 2*qt+1
  load_tile(0);

  for (int kvt = 0; kvt < nkv; ++kvt) {
    __syncthreads();  // previous tile's LDS reads complete
    store_tile();
    __syncthreads();  // tile visible to all waves
    if (kvt + 1 < nkv) load_tile(kvt + 1);  // prefetch overlaps compute

    const int kvb = kvt * KVBLK;
    if (kvb > wq + 31) continue;  // tile fully masked for this wave's rows

    // ---- QK^T (swapped: A=K, B=Q -> C[kv=c*16+4*lg+r][q=lq]) ----
    f32x4 sc[2][4];
#pragma unroll
    for (int rt = 0; rt < 2; ++rt)
#pragma unroll
      for (int c = 0; c < 4; ++c)
        sc[rt][c] = (f32x4){0.f, 0.f, 0.f, 0.f};

#pragma unroll
    for (int c = 0; c < 4; ++c) {
      bf16x8 k0 = *reinterpret_cast<const bf16x8*>(&Ks[c * 16 + lq][8 * lg]);
      bf16x8 k1 = *reinterpret_cast<const bf16x8*>(&Ks[c * 16 + lq][8 * lg + 32]);
#pragma unroll
      for (int rt = 0; rt < 2; ++rt) {
        sc[rt][c] = MFMA32(k0, qf[rt][0], sc[rt][c]);
        sc[rt][c] = MFMA32(k1, qf[rt][1], sc[rt][c]);
      }
    }

    // causal mask (diagonal-region tiles only)
    if (kvb + KVBLK - 1 > wq) {
#pragma unroll
      for (int rt = 0; rt < 2; ++rt) {
        const int q0 = wq + rt * 16 + lq;
#pragma unroll
        for (int c = 0; c < 4; ++c)
#pragma unroll
          for (int r = 0; r < 4; ++r)
            if (kvb + c * 16 + 4 * lg + r > q0) sc[rt][c][r] = -1e30f;
      }
    }

    // ---- online softmax (per q-row = lane lq), P stays in registers ----
    bf16x4 pf[2][4];
    float alpha[2];
#pragma unroll
    for (int rt = 0; rt < 2; ++rt) {
      float c0 = fmaxf(fmaxf(sc[rt][0][0], sc[rt][0][1]), fmaxf(sc[rt][0][2], sc[rt][0][3]));
      float c1 = fmaxf(fmaxf(sc[rt][1][0], sc[rt][1][1]), fmaxf(sc[rt][1][2], sc[rt][1][3]));
      float c2 = fmaxf(fmaxf(sc[rt][2][0], sc[rt][2][1]), fmaxf(sc[rt][2][2], sc[rt][2][3]));
      float c3 = fmaxf(fmaxf(sc[rt][3][0], sc[rt][3][1]), fmaxf(sc[rt][3][2], sc[rt][3][3]));
      float tm = fmaxf(fmaxf(c0, c1), fmaxf(c2, c3));
      tm = fmaxf(tm, __shfl_xor(tm, 16));
      tm = fmaxf(tm, __shfl_xor(tm, 32));
      const float newm = fmaxf(mrun[rt], tm);
      alpha[rt] = EXP2F(mrun[rt] - newm);
      mrun[rt] = newm;

      float ts = 0.f;
#pragma unroll
      for (int c = 0; c < 4; ++c) {
        float p0 = EXP2F(sc[rt][c][0] - newm);
        float p1 = EXP2F(sc[rt][c][1] - newm);
        float p2 = EXP2F(sc[rt][c][2] - newm);
        float p3 = EXP2F(sc[rt][c][3] - newm);
        ts += (p0 + p1) + (p2 + p3);
        union { bf16x4 v; int w[2]; } pp;
        pp.w[0] = f2bf2(p0, p1);
        pp.w[1] = f2bf2(p2, p3);
        pf[rt][c] = pp.v;
      }
      ts += __shfl_xor(ts, 16);
      ts += __shfl_xor(ts, 32);
      lrun[rt] = lrun[rt] * alpha[rt] + ts;
    }

    // ---- rescale acc: alpha lives per q=lq, acc rows are q=4*lg+r -> fetch via shfl ----
#pragma unroll
    for (int rt = 0; rt < 2; ++rt) {
      const float a0 = __shfl(alpha[rt], 4 * lg + 0);
      const float a1 = __shfl(alpha[rt], 4 * lg + 1);
      const float a2 = __shfl(alpha[rt], 4 * lg + 2);
      const float a3 = __shfl(alpha[rt], 4 * lg + 3);
#pragma unroll
      for (int dt = 0; dt < 4; ++dt) {
        acc[rt][dt][0] *= a0;
        acc[rt][dt][1] *= a1;
        acc[rt][dt][2] *= a2;
        acc[rt][dt][3] *= a3;
      }
    }

    // ---- PV: A=P from regs, B=V from VT (contiguous b64 reads), C[q=4*lg+r][d=lq] ----
#pragma unroll
    for (int dt = 0; dt < 4; ++dt) {
#pragma unroll
      for (int c = 0; c < 4; ++c) {
        bf16x4 vf = *reinterpret_cast<const bf16x4*>(&VTs[dt * 16 + lq][c * 16 + 4 * lg]);
        acc[0][dt] = MFMA16(pf[0][c], vf, acc[0][dt]);
        acc[1][dt] = MFMA16(pf[1][c], vf, acc[1][dt]);
      }
    }
  }

  // ---- epilogue: normalize and store (fp32 out) ----
#pragma unroll
  for (int rt = 0; rt < 2; ++rt) {
    const float l0 = __shfl(lrun[rt], 4 * lg + 0);
    const float l1 = __shfl(lrun[rt], 4 * lg + 1);
    const float l2 = __shfl(lrun[rt], 4 * lg + 2);
    const float l3 = __shfl(lrun[rt], 4 * lg + 3);
    const f32x4 linv = {1.f / l0, 1.f / l1, 1.f / l2, 1.f / l3};
#pragma unroll
    for (int dt = 0; dt < 4; ++dt) {
#pragma unroll
      for (int r = 0; r < 4; ++r) {
        out[(size_t)(b * S_LEN + wq + rt * 16 + 4 * lg + r) * (NHEAD * HDIM) + h * HDIM + dt * 16 + lq] =
            acc[rt][dt][r] * linv[r];
      }
    }
  }
}

extern "C" void kernel_launch(void* const* d_in, const int* in_sizes, int n_in,
                              void* d_out, int out_size, void* d_ws, size_t ws_size,
                              hipStream_t stream) {
  const float* qkv = (const float*)d_in[0];
  float* o = (float*)d_out;
  dim3 grid(NQT, 2 * NHEAD);  // (q tiles, B*H) -> remapped inside kernel
  attn_fwd<<<grid, 256, 0, stream>>>(qkv, o);
}